// Round 2
// baseline (25.738 us; speedup 1.0000x reference)
//
#include <hip/hip_runtime.h>
#include <math.h>

#define HH 256
#define WW 256
#define CC 32
#define NN 4

// ---------------- Kernel A: partial mean pool (per plane, per 32-row chunk) ----
__global__ __launch_bounds__(256) void pool_partial(const float* __restrict__ x,
                                                    float* __restrict__ partials) {
    const int bid   = blockIdx.x;        // plane*8 + e
    const int plane = bid >> 3;
    const int e     = bid & 7;
    const float4* xb = (const float4*)(x + (size_t)plane * HH * WW + (size_t)e * 32 * WW);
    const int t = threadIdx.x;
    float s = 0.f;
    #pragma unroll
    for (int k = 0; k < 8; ++k) {        // 32 rows * 256 cols = 2048 float4 / 256 thr
        const float4 v = xb[t + k * 256];
        s += (v.x + v.y) + (v.z + v.w);
    }
    #pragma unroll
    for (int off = 32; off > 0; off >>= 1) s += __shfl_down(s, off, 64);
    __shared__ float wsum[4];
    if ((t & 63) == 0) wsum[t >> 6] = s;
    __syncthreads();
    if (t == 0) partials[bid] = (wsum[0] + wsum[1]) + (wsum[2] + wsum[3]);
}

// ---------------- Kernel B: dynamic filter + stencil + affine (LDS-free stencil) ----
__global__ __launch_bounds__(256) void dynfilt(
    const float* __restrict__ x,
    const float* __restrict__ conv_w,
    const float* __restrict__ bn_gamma, const float* __restrict__ bn_beta,
    const float* __restrict__ bn_mean, const float* __restrict__ bn_var,
    const float* __restrict__ lamb_l, const float* __restrict__ lamb_h,
    const float* __restrict__ inside_all,
    const float* __restrict__ partials,
    float* __restrict__ out)
{
    __shared__ float spooled[CC];
    __shared__ float sfilt[9];
    __shared__ float scoef[3];

    const int bid   = blockIdx.x;        // plane*4 + quad
    const int plane = bid >> 2;
    const int quad  = bid & 3;
    const int n = plane >> 5;
    const int c = plane & 31;
    const int g = c >> 2;                // group = c / 4
    const int t = threadIdx.x;
    const int w = t >> 6;
    const int lane = t & 63;

    // --- reduce pool partials for this batch (32 channels x 8 chunks) ---
    if (t < CC) {
        const float* pp = partials + ((size_t)n * CC + t) * 8;
        float s = 0.f;
        #pragma unroll
        for (int k = 0; k < 8; ++k) s += pp[k];
        spooled[t] = s * (1.0f / (HH * WW));
    }
    __syncthreads();

    // --- filter taps + affine coefs (tiny) ---
    if (t < 9) {
        const int j = g * 9 + t;
        const float* wrow = conv_w + (size_t)j * CC;
        float f = 0.f;
        #pragma unroll
        for (int i = 0; i < CC; ++i) f += spooled[i] * wrow[i];
        f = (f - bn_mean[j]) * bn_gamma[j] * rsqrtf(bn_var[j] + 1e-5f) + bn_beta[j];
        sfilt[t] = tanhf(f);
    } else if (t == 9) {
        const float ia = inside_all[c];
        const float ll = lamb_l[c];
        scoef[0] = (ia + 1.0f) * ll;              // cA
        scoef[1] = -ia * spooled[c] * ll;         // cB
        scoef[2] = lamb_h[c] + 1.0f;              // cC
    }
    __syncthreads();

    const float f0 = sfilt[0], f1 = sfilt[1], f2 = sfilt[2];
    const float f3 = sfilt[3], f4 = sfilt[4], f5 = sfilt[5];
    const float f6 = sfilt[6], f7 = sfilt[7], f8 = sfilt[8];
    const float cA = scoef[0], cB = scoef[1], cC = scoef[2];

    // --- wave-autonomous 16-row strip; lane owns cols [4*lane, 4*lane+3] ---
    const int row0 = (quad * 4 + w) * 16;
    const float* xp = x + (size_t)plane * HH * WW;

    auto load_row = [&](int gr, float4& v, float& l, float& r) {
        gr = (gr < 0) ? -gr : ((gr >= HH) ? (2 * HH - 2 - gr) : gr);
        v = *(const float4*)(xp + (size_t)gr * WW + lane * 4);
        l = __shfl_up(v.w, 1, 64);
        if (lane == 0) l = v.y;          // col -1 reflects to col 1
        r = __shfl_down(v.x, 1, 64);
        if (lane == 63) r = v.z;         // col 256 reflects to col 254
    };

    float  lb[3], rb[3];
    float4 vb[3];
    load_row(row0 - 1, vb[0], lb[0], rb[0]);
    load_row(row0,     vb[1], lb[1], rb[1]);

    float* op = out + (size_t)plane * HH * WW + (size_t)row0 * WW + lane * 4;

    #pragma unroll
    for (int rr = 0; rr < 16; ++rr) {
        const int ia = rr % 3, ib = (rr + 1) % 3, ic = (rr + 2) % 3;
        load_row(row0 + 1 + rr, vb[ic], lb[ic], rb[ic]);

        const float4 a = vb[ia], b = vb[ib], cv = vb[ic];
        const float al = lb[ia], bl = lb[ib], cl = lb[ic];
        const float ar = rb[ia], br = rb[ib], cr = rb[ic];

        const float s0 = f0*al  + f1*a.x + f2*a.y + f3*bl  + f4*b.x + f5*b.y + f6*cl  + f7*cv.x + f8*cv.y;
        const float s1 = f0*a.x + f1*a.y + f2*a.z + f3*b.x + f4*b.y + f5*b.z + f6*cv.x+ f7*cv.y + f8*cv.z;
        const float s2 = f0*a.y + f1*a.z + f2*a.w + f3*b.y + f4*b.z + f5*b.w + f6*cv.y+ f7*cv.z + f8*cv.w;
        const float s3 = f0*a.z + f1*a.w + f2*ar  + f3*b.z + f4*b.w + f5*br  + f6*cv.z+ f7*cv.w + f8*cr;

        float4 o;
        o.x = cA * s0 + cB + cC * b.x;
        o.y = cA * s1 + cB + cC * b.y;
        o.z = cA * s2 + cB + cC * b.z;
        o.w = cA * s3 + cB + cC * b.w;
        *(float4*)(op + (size_t)rr * WW) = o;
    }
}

extern "C" void kernel_launch(void* const* d_in, const int* in_sizes, int n_in,
                              void* d_out, int out_size, void* d_ws, size_t ws_size,
                              hipStream_t stream) {
    const float* x          = (const float*)d_in[0];
    const float* conv_w     = (const float*)d_in[1];
    const float* bn_gamma   = (const float*)d_in[2];
    const float* bn_beta    = (const float*)d_in[3];
    const float* bn_mean    = (const float*)d_in[4];
    const float* bn_var     = (const float*)d_in[5];
    const float* lamb_l     = (const float*)d_in[6];
    const float* lamb_h     = (const float*)d_in[7];
    const float* inside_all = (const float*)d_in[8];
    float* out      = (float*)d_out;
    float* partials = (float*)d_ws;   // NN*CC*8 = 1024 floats

    hipLaunchKernelGGL(pool_partial, dim3(NN * CC * 8), dim3(256), 0, stream, x, partials);
    hipLaunchKernelGGL(dynfilt, dim3(NN * CC * 4), dim3(256), 0, stream,
                       x, conv_w, bn_gamma, bn_beta, bn_mean, bn_var,
                       lamb_l, lamb_h, inside_all, partials, out);
}